// Round 9
// baseline (479.769 us; speedup 1.0000x reference)
//
#include <hip/hip_runtime.h>
#include <hip/hip_bf16.h>

#define BB 8
#define SS 4096
#define HH 2048
#define EE 32
#define FF 128

constexpr size_t DELTA_N = (size_t)BB * SS * HH;  // 67108864
constexpr size_t WELEM = (size_t)EE * FF * HH;    // 8388608 elems per weight tensor
constexpr size_t WBYTES = WELEM * 2;              // 16 MB packed bf16
constexpr size_t HB16_BYTES = (size_t)BB * SS * HH * 2;  // 128 MB

typedef short bf16x8 __attribute__((ext_vector_type(8)));
typedef float f32x4 __attribute__((ext_vector_type(4)));
typedef unsigned short u16;
typedef __attribute__((address_space(3))) unsigned char as3u8;
typedef __attribute__((address_space(1))) const unsigned char as1u8;

__device__ __forceinline__ u16 f2bfu(float x) {
  unsigned int u = __float_as_uint(x);
  u = (u + 0x7FFFu + ((u >> 16) & 1u)) >> 16;  // RNE
  return (u16)u;
}

__device__ __forceinline__ unsigned int pk2(float a, float b) {
  union { __hip_bfloat162 h; unsigned int u; } c;
  c.h = __float22bfloat162_rn(make_float2(a, b));
  return c.u;
}

__device__ __forceinline__ bf16x8 pack8(float4 a, float4 b) {
  union { bf16x8 v; unsigned int u[4]; } r;
  r.u[0] = pk2(a.x, a.y);
  r.u[1] = pk2(a.z, a.w);
  r.u[2] = pk2(b.x, b.y);
  r.u[3] = pk2(b.z, b.w);
  return r.v;
}

__device__ __forceinline__ void glds16(const void* g, void* l) {
  __builtin_amdgcn_global_load_lds((as1u8*)g, (as3u8*)l, 16, 0, 0);
}

// ---------------- k_zero ----------------
__global__ void k_zero(float* __restrict__ ws, int n) {
  int i = blockIdx.x * 256 + threadIdx.x;
  if (i < n) ws[i] = 0.0f;
}

// ---------------- k_pack: weights -> bf16 FRAG-MAJOR order ----------------
// One chunk = 1KB = one wave's 16x16x32 B-fragment: lane l holds col=ct*16+(l&15),
// k = ks*32 + (l>>4)*8 + j  (j=0..7).
// w1p chunk id: ((e*8 + ct)*64 + ks)  [ct: f-tile 0..7, ks: 0..63 over K=2048]
// w2p chunk id: ((e*128 + ct)*4 + ks) [ct: h-tile 0..127, ks: 0..3 over F=128]
__global__ void k_pack(const float* __restrict__ w1, const float* __restrict__ w2,
                       u16* __restrict__ w1p, u16* __restrict__ w2p) {
  unsigned c = blockIdx.x * 256 + threadIdx.x;  // 16B groups (64 per chunk)
  const float* src;
  u16* dst;
  if (c < 1048576u) {
    unsigned e = c >> 15, r = c & 32767u;   // 32768 = 8 ct * 64 ks * 64 l
    unsigned ct = r >> 12;
    unsigned ks = (r >> 6) & 63u;
    unsigned l = r & 63u;
    unsigned f = ct * 16u + (l & 15u);
    unsigned k = ks * 32u + ((l >> 4) << 3);
    src = w1 + ((size_t)(e * 128u + f)) * HH + k;
    dst = w1p + (size_t)c * 8;
  } else {
    unsigned c2 = c - 1048576u;
    unsigned e = c2 >> 15, r = c2 & 32767u;  // 32768 = 128 ct * 4 ks * 64 l
    unsigned ct = r >> 8;
    unsigned ks = (r >> 6) & 3u;
    unsigned l = r & 63u;
    unsigned h = ct * 16u + (l & 15u);
    unsigned k = ks * 32u + ((l >> 4) << 3);
    src = w2 + ((size_t)(e * 2048u + h)) * FF + k;
    dst = w2p + (size_t)c2 * 8;
  }
  float4 a = *(const float4*)src;
  float4 b = *(const float4*)(src + 4);
  *(bf16x8*)dst = pack8(a, b);
}

// ---------------- k_pooltile (proven): psum + bf16 swizzled hidden image ----------
__global__ __launch_bounds__(512) void k_pooltile(const float* __restrict__ hidden,
                                                  u16* __restrict__ hb16,
                                                  float* __restrict__ psum) {
  const int b  = blockIdx.x >> 6;
  const int st = blockIdx.x & 63;
  const int t  = threadIdx.x;

  const float* src = hidden + ((size_t)b * SS + st * 64) * HH + t * 4;
  char* dbase = (char*)hb16 + (size_t)(b * 64 + st) * 262144 + (size_t)(t >> 4) * 8192;
  const int kq = (t & 15) * 8;

  float4 s = make_float4(0.f, 0.f, 0.f, 0.f);
  for (int r = 0; r < 64; ++r) {
    float4 v = *(const float4*)(src + (size_t)r * HH);
    s.x += v.x; s.y += v.y; s.z += v.z; s.w += v.w;
    *(uint2*)(dbase + r * 128 + (kq ^ ((r & 7) << 4))) =
        make_uint2(pk2(v.x, v.y), pk2(v.z, v.w));
  }
  float* pp = psum + (size_t)b * HH + t * 4;
  atomicAdd(pp + 0, s.x);
  atomicAdd(pp + 1, s.y);
  atomicAdd(pp + 2, s.z);
  atomicAdd(pp + 3, s.w);
}

// ---------------- k_logits (proven) ----------------
__global__ void k_logits(const float* __restrict__ psum, const float* __restrict__ rw,
                         float* __restrict__ logits) {
  int b = blockIdx.x >> 5;
  int e = blockIdx.x & 31;
  int tid = threadIdx.x;
  float acc = 0.0f;
  const float* ps = psum + (size_t)b * HH;
  const float* wr = rw + (size_t)e * HH;
  for (int h = tid; h < HH; h += 256) acc = fmaf(ps[h], wr[h], acc);
  __shared__ float red[256];
  red[tid] = acc;
  __syncthreads();
  for (int w = 128; w > 0; w >>= 1) {
    if (tid < w) red[tid] += red[tid + w];
    __syncthreads();
  }
  if (tid == 0) logits[blockIdx.x] = red[0] * (1.0f / (float)SS);
}

// ---------------- k_topk (proven) ----------------
__global__ void k_topk(const float* __restrict__ logits, const float* __restrict__ rb,
                       const float* __restrict__ counts, const float* __restrict__ drift,
                       int* __restrict__ sel, float* __restrict__ pscale,
                       float* __restrict__ out) {
  int t = threadIdx.x;
  int b = t >> 5, e = t & 31;
  float total = 0.0f, cmax = 0.0f, dmax = 0.0f;
  for (int i = 0; i < EE; ++i) {
    float c = counts[i]; total += c; cmax = fmaxf(cmax, c);
    float d = drift[i];  dmax = fmaxf(dmax, d);
  }
  float cnt = counts[e], dr = drift[e];
  float usage = cnt / fmaxf(total, 1e-8f);
  float bonus = (total > 0.0f) ? 0.1f * (1.0f - usage) : 0.0f;
  float un = cnt / fmaxf(cmax, 1e-8f);
  float dn = dr / fmaxf(dmax, 1e-8f);
  float l = logits[t] + rb[e] + bonus - 0.05f * (un + dn);

  float m = l;
  for (int w = 16; w; w >>= 1) m = fmaxf(m, __shfl_xor(m, w, 32));
  float p = expf(l - m);
  float ssum = p;
  for (int w = 16; w; w >>= 1) ssum += __shfl_xor(ssum, w, 32);
  float prob = p / ssum;
  out[DELTA_N + 32 + t] = prob;

  float v1 = prob; int i1 = e;
  for (int w = 16; w; w >>= 1) {
    float ov = __shfl_xor(v1, w, 32); int oi = __shfl_xor(i1, w, 32);
    if (ov > v1 || (ov == v1 && oi < i1)) { v1 = ov; i1 = oi; }
  }
  float v2 = (e == i1) ? -1.0f : prob; int i2 = e;
  for (int w = 16; w; w >>= 1) {
    float ov = __shfl_xor(v2, w, 32); int oi = __shfl_xor(i2, w, 32);
    if (ov > v2 || (ov == v2 && oi < i2)) { v2 = ov; i2 = oi; }
  }
  if (e == 0) {
    float denom = fmaxf(v1 + v2, 1e-8f);
    float tp0 = v1 / denom, tp1 = v2 / denom;
    sel[b * 2 + 0] = i1;
    sel[b * 2 + 1] = i2;
    pscale[b * 2 + 0] = tp0;
    pscale[b * 2 + 1] = tp1;
    out[DELTA_N + 0 + b * 2 + 0] = (float)i1;
    out[DELTA_N + 0 + b * 2 + 1] = (float)i2;
    out[DELTA_N + 16 + b * 2 + 0] = tp0;
    out[DELTA_N + 16 + b * 2 + 1] = tp1;
  }
}

// ---------------- k_ffn3: A via LDS, B-frags direct from global (frag-major) -----
// grid 512: b = bid&7 (XCD), st = bid>>3, rows [st*64, st*64+64). 512 thr = 8 waves.
// GEMM1: M=64 N=256 K=2048, BK=64; waves 2(row)x4(col), wave tile 32x64.
//   A from LDS dbuf (hb16 image, glds); B-frags from w1p (global, L2-hot). 1 barrier/iter.
// GEMM2: M=64 N=2048 K=256; wave owns 64x32 chunk per pass, 8 passes. A from sG,
//   B-frags from w2p (global). ZERO barriers after the sG barrier.
// LDS 48KB: A dbuf [0,16K) + sG [16K,48K).
__global__ __launch_bounds__(512, 4) void k_ffn3(
    const u16* __restrict__ hb16, const float* __restrict__ bs1,
    const float* __restrict__ bs2, const u16* __restrict__ w1p,
    const u16* __restrict__ w2p, const int* __restrict__ sel,
    const float* __restrict__ pscale, float* __restrict__ out) {
  __shared__ __align__(16) char smem[49152];

  const int t    = threadIdx.x;
  const int lane = t & 63;
  const int wv   = t >> 6;
  const int l15  = lane & 15;
  const int lk   = lane >> 4;

  const int bid = blockIdx.x;
  const int b   = bid & 7;
  const int st  = bid >> 3;

  const int e0 = sel[2 * b], e1 = sel[2 * b + 1];
  const float p0 = pscale[2 * b], p1 = pscale[2 * b + 1];

  // GEMM1 wave tile
  const int wr = wv >> 2, wc = wv & 3;
  const int RB = wr * 32, CB = wc * 64;
  const int es1 = (wc < 2) ? e0 : e1;     // expert for this wave's cols
  const int gctb = (wc & 1) * 4;          // f-tile base within expert

  const char* hsrc = (const char*)hb16 + (size_t)(b * 64 + st) * 262144 + (size_t)t * 16;
  const char* w1c = (const char*)w1p + ((size_t)(es1 * 8 + gctb)) * 65536 + (size_t)lane * 16;

  f32x4 zero = {0.f, 0.f, 0.f, 0.f};
  f32x4 acc1[2][4];
#pragma unroll
  for (int i = 0; i < 2; ++i)
#pragma unroll
    for (int j = 0; j < 4; ++j) acc1[i][j] = zero;

  // prologue: stage A slab 0
  glds16(hsrc, &smem[(size_t)t * 16]);
  __syncthreads();

  // GEMM1: 32 iters x BK=64
  for (int j = 0; j < 32; ++j) {
    const int cb = j & 1, nb = cb ^ 1;
    if (j < 31) glds16(hsrc + (size_t)(j + 1) * 8192, &smem[nb * 8192 + (size_t)t * 16]);
    const char* sa = &smem[cb * 8192];
#pragma unroll
    for (int kk = 0; kk < 2; ++kk) {
      bf16x8 af[2], bv[4];
#pragma unroll
      for (int ct = 0; ct < 4; ++ct)
        bv[ct] = *(const bf16x8*)(w1c + (size_t)ct * 65536 + (size_t)(j * 2 + kk) * 1024);
#pragma unroll
      for (int rt = 0; rt < 2; ++rt) {
        int row = RB + rt * 16 + l15;
        af[rt] = *(const bf16x8*)(sa + row * 128 + ((kk * 64 + lk * 16) ^ ((row & 7) << 4)));
      }
#pragma unroll
      for (int rt = 0; rt < 2; ++rt)
#pragma unroll
        for (int ct = 0; ct < 4; ++ct)
          acc1[rt][ct] = __builtin_amdgcn_mfma_f32_16x16x32_bf16(af[rt], bv[ct], acc1[rt][ct], 0, 0, 0);
    }
    __syncthreads();
  }

  // epilogue 1: bias + exact gelu + prob scale -> sG [16K,48K)
#pragma unroll
  for (int ct = 0; ct < 4; ++ct) {
    int c = CB + ct * 16 + l15;
    int ec = (c < 128) ? e0 : e1;
    float pc = (c < 128) ? p0 : p1;
    float bias = bs1[ec * FF + (c & 127)];
#pragma unroll
    for (int rt = 0; rt < 2; ++rt)
#pragma unroll
      for (int r = 0; r < 4; ++r) {
        int row = RB + rt * 16 + lk * 4 + r;
        float x = acc1[rt][ct][r] + bias;
        float g = 0.5f * x * (1.0f + erff(x * 0.70710678118654752f));
        *(u16*)&smem[16384 + row * 512 + ((c * 2) ^ ((row & 7) << 4))] = f2bfu(pc * g);
      }
  }
  __syncthreads();

  // GEMM2: barrier-free. Wave wv handles col chunk (sp*8+wv)*32 per pass.
  float* obase = out + ((size_t)b * SS + st * 64) * HH;
  const char* sg = &smem[16384];
  const char* w2c0 = (const char*)w2p + (size_t)e0 * 524288 + (size_t)lane * 16;
  const char* w2c1 = (const char*)w2p + (size_t)e1 * 524288 + (size_t)lane * 16;

#pragma unroll 1
  for (int sp = 0; sp < 8; ++sp) {
    const int colbase = (sp * 8 + wv) * 32;
    f32x4 acc2[4][2];
#pragma unroll
    for (int i = 0; i < 4; ++i) { acc2[i][0] = zero; acc2[i][1] = zero; }
#pragma unroll
    for (int k32 = 0; k32 < 8; ++k32) {
      const char* wp = (k32 < 4) ? w2c0 : w2c1;
      const int ks = k32 & 3;
      bf16x8 bv[2], af[4];
#pragma unroll
      for (int c2 = 0; c2 < 2; ++c2) {
        int gct = (colbase >> 4) + c2;
        bv[c2] = *(const bf16x8*)(wp + ((size_t)gct * 4 + ks) * 1024);
      }
#pragma unroll
      for (int rt = 0; rt < 4; ++rt) {
        int row = rt * 16 + l15;
        af[rt] = *(const bf16x8*)(sg + row * 512 + ((k32 * 64 + lk * 16) ^ ((row & 7) << 4)));
      }
#pragma unroll
      for (int rt = 0; rt < 4; ++rt)
#pragma unroll
        for (int c2 = 0; c2 < 2; ++c2)
          acc2[rt][c2] = __builtin_amdgcn_mfma_f32_16x16x32_bf16(af[rt], bv[c2], acc2[rt][c2], 0, 0, 0);
    }
#pragma unroll
    for (int c2 = 0; c2 < 2; ++c2) {
      int col = colbase + c2 * 16 + l15;
      float bias = p0 * bs2[(size_t)e0 * HH + col] + p1 * bs2[(size_t)e1 * HH + col];
#pragma unroll
      for (int rt = 0; rt < 4; ++rt)
#pragma unroll
        for (int r = 0; r < 4; ++r) {
          int row = rt * 16 + lk * 4 + r;
          obase[(size_t)row * HH + col] = acc2[rt][c2][r] + bias;
        }
    }
  }
}

// ================= fallback (round-5 proven, needs no packed ws) =================
__global__ void k_pool_logits(const float* __restrict__ hidden,
                              const float* __restrict__ rw,
                              float* __restrict__ logits) {
  const int b  = blockIdx.x >> 6;
  const int hc = (blockIdx.x >> 3) & 7;
  const int sq = blockIdx.x & 7;
  const int t  = threadIdx.x;
  const int tx = t & 63;
  const int qq = t >> 6;
  const int h0 = hc * 256;

  const float* p = hidden + ((size_t)b * SS + sq * 512 + qq * 128) * HH + h0 + tx * 4;
  float4 s = make_float4(0.f, 0.f, 0.f, 0.f);
  for (int i = 0; i < 128; ++i) {
    float4 v = *(const float4*)(p + (size_t)i * HH);
    s.x += v.x; s.y += v.y; s.z += v.z; s.w += v.w;
  }
  __shared__ float ps[4][256];
  __shared__ float pl[256];
  *(float4*)&ps[qq][tx * 4] = s;
  __syncthreads();
  pl[t] = ps[0][t] + ps[1][t] + ps[2][t] + ps[3][t];
  __syncthreads();

  const int e = t >> 3, part = t & 7;
  const float* wrp = rw + (size_t)e * HH + h0 + part * 32;
  float v = 0.f;
#pragma unroll
  for (int m = 0; m < 32; ++m) v += pl[part * 32 + m] * wrp[m];
  v += __shfl_xor(v, 1, 8);
  v += __shfl_xor(v, 2, 8);
  v += __shfl_xor(v, 4, 8);
  if (part == 0) atomicAdd(&logits[b * EE + e], v * (1.0f / (float)SS));
}

__global__ __launch_bounds__(512, 2) void k_ffn_fb(
    const float* __restrict__ hidden, const float* __restrict__ w1,
    const float* __restrict__ b1, const float* __restrict__ w2,
    const float* __restrict__ b2, const int* __restrict__ sel,
    const float* __restrict__ pscale, float* __restrict__ out) {
  __shared__ unsigned char sA[2][64 * 128];
  __shared__ unsigned char sG[64 * 512];

  const int t    = threadIdx.x;
  const int lane = t & 63;
  const int wv   = t >> 6;
  const int wr   = wv >> 2;
  const int wc   = wv & 3;
  const int l15  = lane & 15;
  const int lk   = lane >> 4;

  const int bid = blockIdx.x;
  const int b   = bid & 7;
  const int s0  = (bid >> 3) * 64;

  const int e0 = sel[2 * b], e1 = sel[2 * b + 1];
  const float p0 = pscale[2 * b], p1 = pscale[2 * b + 1];

  const float* hbase = hidden + ((size_t)b * SS + s0) * HH;
  const int srow = t >> 4;
  const int skq  = t & 15;

  float4 R[2];
  const float* wp[4];
#pragma unroll
  for (int ct = 0; ct < 4; ++ct) {
    int cbase = wc * 64 + ct * 16;
    int ec = (cbase < 128) ? e0 : e1;
    int f  = (cbase & 127) + l15;
    wp[ct] = w1 + ((size_t)ec * FF + f) * HH + lk * 8;
  }

  f32x4 zero = {0.f, 0.f, 0.f, 0.f};
  f32x4 acc1[2][4];
#pragma unroll
  for (int i = 0; i < 2; ++i)
#pragma unroll
    for (int j = 0; j < 4; ++j) acc1[i][j] = zero;

#pragma unroll
  for (int p = 0; p < 2; ++p)
    R[p] = *(const float4*)(hbase + (size_t)(srow + 32 * p) * HH + skq * 4);
#pragma unroll
  for (int p = 0; p < 2; ++p) {
    int row = srow + 32 * p;
    int addr = row * 128 + ((skq * 8) ^ ((row & 7) << 4));
    *(uint2*)(&sA[0][addr]) = make_uint2(pk2(R[p].x, R[p].y), pk2(R[p].z, R[p].w));
  }
  __syncthreads();

  for (int it = 0; it < 32; ++it) {
    const int buf = it & 1;
    if (it < 31) {
      const int k0 = (it + 1) * 64;
#pragma unroll
      for (int p = 0; p < 2; ++p)
        R[p] = *(const float4*)(hbase + (size_t)(srow + 32 * p) * HH + k0 + skq * 4);
    }
#pragma unroll
    for (int kk = 0; kk < 2; ++kk) {
      bf16x8 a[2];
#pragma unroll
      for (int rt = 0; rt < 2; ++rt) {
        int row = wr * 32 + rt * 16 + l15;
        a[rt] = *(const bf16x8*)(&sA[buf][row * 128 + ((kk * 64 + lk * 16) ^ ((row & 7) << 4))]);
      }
#pragma unroll
      for (int ct = 0; ct < 4; ++ct) {
        const float* q = wp[ct] + it * 64 + kk * 32;
        bf16x8 bfr = pack8(*(const float4*)q, *(const float4*)(q + 4));
#pragma unroll
        for (int rt = 0; rt < 2; ++rt)
          acc1[rt][ct] = __builtin_amdgcn_mfma_f32_16x16x32_bf16(a[rt], bfr, acc1[rt][ct], 0, 0, 0);
      }
    }
    if (it < 31) {
#pragma unroll
      for (int p = 0; p < 2; ++p) {
        int row = srow + 32 * p;
        int addr = row * 128 + ((skq * 8) ^ ((row & 7) << 4));
        *(uint2*)(&sA[buf ^ 1][addr]) = make_uint2(pk2(R[p].x, R[p].y), pk2(R[p].z, R[p].w));
      }
    }
    __syncthreads();
  }

#pragma unroll
  for (int ct = 0; ct < 4; ++ct) {
    int c = wc * 64 + ct * 16 + l15;
    int ec = (c < 128) ? e0 : e1;
    float pc = (c < 128) ? p0 : p1;
    float bias = b1[ec * FF + (c & 127)];
#pragma unroll
    for (int rt = 0; rt < 2; ++rt)
#pragma unroll
      for (int r = 0; r < 4; ++r) {
        int row = wr * 32 + rt * 16 + lk * 4 + r;
        float x = acc1[rt][ct][r] + bias;
        float g = 0.5f * x * (1.0f + erff(x * 0.70710678118654752f));
        int addr = row * 512 + ((c * 2) ^ ((row & 7) << 4));
        *(u16*)(&sG[addr]) = f2bfu(pc * g);
      }
  }
  __syncthreads();

  bf16x8 pa[2][8];
#pragma unroll
  for (int rt = 0; rt < 2; ++rt) {
    int row = wr * 32 + rt * 16 + l15;
#pragma unroll
    for (int ks = 0; ks < 8; ++ks)
      pa[rt][ks] = *(const bf16x8*)(&sG[row * 512 + ((ks * 64 + lk * 16) ^ ((row & 7) << 4))]);
  }

  float* obase = out + ((size_t)b * SS + s0) * HH;
  for (int ct = 0; ct < 32; ++ct) {
    const int h = wc * 512 + ct * 16 + l15;
    f32x4 acc[2];
    acc[0] = zero; acc[1] = zero;
    const float* q0 = w2 + ((size_t)e0 * HH + h) * FF + lk * 8;
    const float* q1 = w2 + ((size_t)e1 * HH + h) * FF + lk * 8;
#pragma unroll
    for (int ks = 0; ks < 8; ++ks) {
      const float* q = (ks < 4 ? q0 : q1) + (ks & 3) * 32;
      bf16x8 bfr = pack8(*(const float4*)q, *(const float4*)(q + 4));
#pragma unroll
      for (int rt = 0; rt < 2; ++rt)
        acc[rt] = __builtin_amdgcn_mfma_f32_16x16x32_bf16(pa[rt][ks], bfr, acc[rt], 0, 0, 0);
    }
    float bias = p0 * b2[(size_t)e0 * HH + h] + p1 * b2[(size_t)e1 * HH + h];
#pragma unroll
    for (int rt = 0; rt < 2; ++rt)
#pragma unroll
      for (int r = 0; r < 4; ++r) {
        int row = wr * 32 + rt * 16 + lk * 4 + r;
        obase[(size_t)row * HH + h] = acc[rt][r] + bias;
      }
  }
}

extern "C" void kernel_launch(void* const* d_in, const int* in_sizes, int n_in,
                              void* d_out, int out_size, void* d_ws, size_t ws_size,
                              hipStream_t stream) {
  const float* hidden   = (const float*)d_in[0];
  const float* router_w = (const float*)d_in[1];
  const float* router_b = (const float*)d_in[2];
  const float* w1       = (const float*)d_in[3];
  const float* b1       = (const float*)d_in[4];
  const float* w2       = (const float*)d_in[5];
  const float* b2       = (const float*)d_in[6];
  const float* counts   = (const float*)d_in[7];
  const float* drift    = (const float*)d_in[8];
  float* out            = (float*)d_out;

  float* logits = (float*)d_ws;                     // 256 f @ 0
  int*   sel    = (int*)((char*)d_ws + 1024);       // 16 int
  float* pscale = (float*)((char*)d_ws + 1088);     // 16 f
  float* psum   = (float*)((char*)d_ws + 4096);     // BB*HH f (64KB)

  const size_t need_big = 131072 + 2 * WBYTES + HB16_BYTES;

  if (ws_size >= need_big) {
    u16* w1p  = (u16*)((char*)d_ws + 131072);
    u16* w2p  = (u16*)((char*)d_ws + 131072 + WBYTES);
    u16* hb16 = (u16*)((char*)d_ws + 131072 + 2 * WBYTES);
    k_zero<<<68, 256, 0, stream>>>(logits, 17408);
    k_pack<<<8192, 256, 0, stream>>>(w1, w2, w1p, w2p);
    k_pooltile<<<512, 512, 0, stream>>>(hidden, hb16, psum);
    k_logits<<<256, 256, 0, stream>>>(psum, router_w, logits);
    k_topk<<<1, 256, 0, stream>>>(logits, router_b, counts, drift, sel, pscale, out);
    k_ffn3<<<512, 512, 0, stream>>>(hb16, b1, b2, w1p, w2p, sel, pscale, out);
  } else {
    k_zero<<<2, 256, 0, stream>>>(logits, 288);
    k_pool_logits<<<512, 256, 0, stream>>>(hidden, router_w, logits);
    k_topk<<<1, 256, 0, stream>>>(logits, router_b, counts, drift, sel, pscale, out);
    k_ffn_fb<<<512, 512, 0, stream>>>(hidden, w1, b1, w2, b2, sel, pscale, out);
  }
}

// Round 10
// 279.069 us; speedup vs baseline: 1.7192x; 1.7192x over previous
//
#include <hip/hip_runtime.h>
#include <hip/hip_bf16.h>

#define BB 8
#define SS 4096
#define HH 2048
#define EE 32
#define FF 128

constexpr size_t DELTA_N = (size_t)BB * SS * HH;  // 67108864
constexpr size_t WELEM = (size_t)EE * FF * HH;    // 8388608 elems per weight tensor
constexpr size_t WBYTES = WELEM * 2;              // 16 MB packed bf16
constexpr size_t HB16_BYTES = (size_t)BB * SS * HH * 2;  // 128 MB

typedef short bf16x8 __attribute__((ext_vector_type(8)));
typedef float f32x4 __attribute__((ext_vector_type(4)));
typedef unsigned short u16;
typedef __attribute__((address_space(3))) unsigned char as3u8;
typedef __attribute__((address_space(1))) const unsigned char as1u8;

#define WAITV(N)                                             \
  do {                                                       \
    asm volatile("s_waitcnt vmcnt(" #N ")" ::: "memory");    \
    __builtin_amdgcn_sched_barrier(0);                       \
  } while (0)
#define BARRIER()                                            \
  do {                                                       \
    __builtin_amdgcn_s_barrier();                            \
    __builtin_amdgcn_sched_barrier(0);                       \
  } while (0)

__device__ __forceinline__ u16 f2bfu(float x) {
  unsigned int u = __float_as_uint(x);
  u = (u + 0x7FFFu + ((u >> 16) & 1u)) >> 16;  // RNE
  return (u16)u;
}

__device__ __forceinline__ unsigned int pk2(float a, float b) {
  union { __hip_bfloat162 h; unsigned int u; } c;
  c.h = __float22bfloat162_rn(make_float2(a, b));
  return c.u;
}

__device__ __forceinline__ bf16x8 pack8(float4 a, float4 b) {
  union { bf16x8 v; unsigned int u[4]; } r;
  r.u[0] = pk2(a.x, a.y);
  r.u[1] = pk2(a.z, a.w);
  r.u[2] = pk2(b.x, b.y);
  r.u[3] = pk2(b.z, b.w);
  return r.v;
}

__device__ __forceinline__ void glds16(const void* g, void* l) {
  __builtin_amdgcn_global_load_lds((as1u8*)g, (as3u8*)l, 16, 0, 0);
}

// ---------------- k_zero ----------------
__global__ void k_zero(float* __restrict__ ws, int n) {
  int i = blockIdx.x * 256 + threadIdx.x;
  if (i < n) ws[i] = 0.0f;
}

// ---------------- k_pack: weights -> bf16 LDS-image order (round-8 proven) -------
__global__ void k_pack(const float* __restrict__ w1, const float* __restrict__ w2,
                       u16* __restrict__ w1p, u16* __restrict__ w2p) {
  unsigned c = blockIdx.x * 256 + threadIdx.x;
  const float* src;
  u16* dst;
  if (c < 1048576u) {
    unsigned e = c >> 15, ci = c & 32767u;
    unsigned it = ci >> 10;
    unsigned cb = (ci & 1023u) * 16u;
    unsigned col = cb >> 7;
    unsigned kb = (cb & 127u) ^ ((col & 7u) << 4);
    unsigned k = it * 64u + (kb >> 1);
    src = w1 + ((size_t)(e * 128u + col) * HH + k);
    dst = w1p + (size_t)c * 8;
  } else {
    unsigned c2 = c - 1048576u;
    unsigned e = c2 >> 15, ci = c2 & 32767u;
    unsigned h = ci >> 4;
    unsigned cb = (ci & 15u) * 16u;
    unsigned kb = cb ^ ((h & 7u) << 4);
    unsigned f = kb >> 1;
    src = w2 + ((size_t)(e * 2048u + h) * FF + f);
    dst = w2p + (size_t)c2 * 8;
  }
  float4 a = *(const float4*)src;
  float4 b = *(const float4*)(src + 4);
  *(bf16x8*)dst = pack8(a, b);
}

// ---------------- k_pooltile (proven) ----------------
__global__ __launch_bounds__(512) void k_pooltile(const float* __restrict__ hidden,
                                                  u16* __restrict__ hb16,
                                                  float* __restrict__ psum) {
  const int b  = blockIdx.x >> 6;
  const int st = blockIdx.x & 63;
  const int t  = threadIdx.x;

  const float* src = hidden + ((size_t)b * SS + st * 64) * HH + t * 4;
  char* dbase = (char*)hb16 + (size_t)(b * 64 + st) * 262144 + (size_t)(t >> 4) * 8192;
  const int kq = (t & 15) * 8;

  float4 s = make_float4(0.f, 0.f, 0.f, 0.f);
  for (int r = 0; r < 64; ++r) {
    float4 v = *(const float4*)(src + (size_t)r * HH);
    s.x += v.x; s.y += v.y; s.z += v.z; s.w += v.w;
    *(uint2*)(dbase + r * 128 + (kq ^ ((r & 7) << 4))) =
        make_uint2(pk2(v.x, v.y), pk2(v.z, v.w));
  }
  float* pp = psum + (size_t)b * HH + t * 4;
  atomicAdd(pp + 0, s.x);
  atomicAdd(pp + 1, s.y);
  atomicAdd(pp + 2, s.z);
  atomicAdd(pp + 3, s.w);
}

// ---------------- k_logits (proven) ----------------
__global__ void k_logits(const float* __restrict__ psum, const float* __restrict__ rw,
                         float* __restrict__ logits) {
  int b = blockIdx.x >> 5;
  int e = blockIdx.x & 31;
  int tid = threadIdx.x;
  float acc = 0.0f;
  const float* ps = psum + (size_t)b * HH;
  const float* wr = rw + (size_t)e * HH;
  for (int h = tid; h < HH; h += 256) acc = fmaf(ps[h], wr[h], acc);
  __shared__ float red[256];
  red[tid] = acc;
  __syncthreads();
  for (int w = 128; w > 0; w >>= 1) {
    if (tid < w) red[tid] += red[tid + w];
    __syncthreads();
  }
  if (tid == 0) logits[blockIdx.x] = red[0] * (1.0f / (float)SS);
}

// ---------------- k_topk (proven) ----------------
__global__ void k_topk(const float* __restrict__ logits, const float* __restrict__ rb,
                       const float* __restrict__ counts, const float* __restrict__ drift,
                       int* __restrict__ sel, float* __restrict__ pscale,
                       float* __restrict__ out) {
  int t = threadIdx.x;
  int b = t >> 5, e = t & 31;
  float total = 0.0f, cmax = 0.0f, dmax = 0.0f;
  for (int i = 0; i < EE; ++i) {
    float c = counts[i]; total += c; cmax = fmaxf(cmax, c);
    float d = drift[i];  dmax = fmaxf(dmax, d);
  }
  float cnt = counts[e], dr = drift[e];
  float usage = cnt / fmaxf(total, 1e-8f);
  float bonus = (total > 0.0f) ? 0.1f * (1.0f - usage) : 0.0f;
  float un = cnt / fmaxf(cmax, 1e-8f);
  float dn = dr / fmaxf(dmax, 1e-8f);
  float l = logits[t] + rb[e] + bonus - 0.05f * (un + dn);

  float m = l;
  for (int w = 16; w; w >>= 1) m = fmaxf(m, __shfl_xor(m, w, 32));
  float p = expf(l - m);
  float ssum = p;
  for (int w = 16; w; w >>= 1) ssum += __shfl_xor(ssum, w, 32);
  float prob = p / ssum;
  out[DELTA_N + 32 + t] = prob;

  float v1 = prob; int i1 = e;
  for (int w = 16; w; w >>= 1) {
    float ov = __shfl_xor(v1, w, 32); int oi = __shfl_xor(i1, w, 32);
    if (ov > v1 || (ov == v1 && oi < i1)) { v1 = ov; i1 = oi; }
  }
  float v2 = (e == i1) ? -1.0f : prob; int i2 = e;
  for (int w = 16; w; w >>= 1) {
    float ov = __shfl_xor(v2, w, 32); int oi = __shfl_xor(i2, w, 32);
    if (ov > v2 || (ov == v2 && oi < i2)) { v2 = ov; i2 = oi; }
  }
  if (e == 0) {
    float denom = fmaxf(v1 + v2, 1e-8f);
    float tp0 = v1 / denom, tp1 = v2 / denom;
    sel[b * 2 + 0] = i1;
    sel[b * 2 + 1] = i2;
    pscale[b * 2 + 0] = tp0;
    pscale[b * 2 + 1] = tp1;
    out[DELTA_N + 0 + b * 2 + 0] = (float)i1;
    out[DELTA_N + 0 + b * 2 + 1] = (float)i2;
    out[DELTA_N + 16 + b * 2 + 0] = tp0;
    out[DELTA_N + 16 + b * 2 + 1] = tp1;
  }
}

// ---------------- k_ffn2: round-8 structure + T4 counted-vmcnt pipeline ----------
// grid 512: b = bid&7 (XCD), st = bid>>3. 512 thr = 8 waves.
// GEMM1 (waves 2x4): M=64 N=256 K=2048, BK=64; A/B glds dbuf; wait vmcnt(5).
// GEMM2 (waves 4x2): M=64 N=2048 K=256; n-chunk 32, TRIPLE-buffered tiles;
//   1 barrier/iter, wait vmcnt(6) (4 stores + 2 loads in-order ahead).
// LDS 80KB: ph1 A dbuf [0,16K) + B dbuf [16K,80K); ph2 sG [0,32K) + 3x16K [32K,80K).
__global__ __launch_bounds__(512, 4) void k_ffn2(
    const u16* __restrict__ hb16, const float* __restrict__ bs1,
    const float* __restrict__ bs2, const u16* __restrict__ w1p,
    const u16* __restrict__ w2p, const int* __restrict__ sel,
    const float* __restrict__ pscale, float* __restrict__ out) {
  __shared__ __align__(16) char smem[81920];

  const int t    = threadIdx.x;
  const int lane = t & 63;
  const int wv   = t >> 6;
  const int l15  = lane & 15;
  const int lk   = lane >> 4;

  const int bid = blockIdx.x;
  const int b   = bid & 7;
  const int st  = bid >> 3;

  const int e0 = sel[2 * b], e1 = sel[2 * b + 1];
  const float p0 = pscale[2 * b], p1 = pscale[2 * b + 1];

  const int wr = wv >> 2, wc = wv & 3;
  const int RB = wr * 32, CB = wc * 64;

  const char* hsrc = (const char*)hb16 + (size_t)(b * 64 + st) * 262144 + (size_t)t * 16;
  const size_t eB1 = (size_t)((wv < 4) ? e0 : e1) * 524288;
  const char* bsrc = (const char*)w1p + eB1 + (size_t)(wv & 3) * 4096 + (size_t)lane * 16;

  f32x4 zero = {0.f, 0.f, 0.f, 0.f};
  f32x4 acc1[2][4];
#pragma unroll
  for (int i = 0; i < 2; ++i)
#pragma unroll
    for (int j = 0; j < 4; ++j) acc1[i][j] = zero;

  // ---- stage helper: tile j -> buffer bb (5 vmcnt items per thread)
  auto STAGE1 = [&](int bb, int j) {
    glds16(hsrc + (size_t)j * 8192, &smem[bb * 8192 + (size_t)t * 16]);
    const char* s = bsrc + (size_t)j * 16384;
    char* d = &smem[16384 + bb * 32768 + wv * 4096 + lane * 16];
#pragma unroll
    for (int r = 0; r < 4; ++r) glds16(s + r * 1024, d + r * 1024);
  };

  // prologue: depth-2 prefetch
  STAGE1(0, 0);
  STAGE1(1, 1);

  // ---- GEMM1: 32 iters x BK=64, counted-vmcnt pipeline
#pragma unroll 1
  for (int j = 0; j < 32; ++j) {
    if (j < 31) { WAITV(5); } else { WAITV(0); }
    BARRIER();
    const int cb = j & 1;
    const char* sa = &smem[cb * 8192];
    const char* sb = &smem[16384 + cb * 32768];
#pragma unroll
    for (int kk = 0; kk < 2; ++kk) {
      bf16x8 af[2], bv[4];
#pragma unroll
      for (int rt = 0; rt < 2; ++rt) {
        int row = RB + rt * 16 + l15;
        af[rt] = *(const bf16x8*)(sa + row * 128 + ((kk * 64 + lk * 16) ^ ((row & 7) << 4)));
      }
#pragma unroll
      for (int ct = 0; ct < 4; ++ct) {
        int col = CB + ct * 16 + l15;
        bv[ct] = *(const bf16x8*)(sb + col * 128 + ((kk * 64 + lk * 16) ^ ((col & 7) << 4)));
      }
#pragma unroll
      for (int rt = 0; rt < 2; ++rt)
#pragma unroll
        for (int ct = 0; ct < 4; ++ct)
          acc1[rt][ct] = __builtin_amdgcn_mfma_f32_16x16x32_bf16(af[rt], bv[ct], acc1[rt][ct], 0, 0, 0);
    }
    BARRIER();
    if (j < 30) STAGE1(cb, j + 2);
  }

  // ---- epilogue 1: bias + exact gelu + prob scale -> sG [0,32K)
#pragma unroll
  for (int ct = 0; ct < 4; ++ct) {
    int c = CB + ct * 16 + l15;
    int ec = (c < 128) ? e0 : e1;
    float pc = (c < 128) ? p0 : p1;
    float bias = bs1[ec * FF + (c & 127)];
#pragma unroll
    for (int rt = 0; rt < 2; ++rt)
#pragma unroll
      for (int r = 0; r < 4; ++r) {
        int row = RB + rt * 16 + lk * 4 + r;
        float x = acc1[rt][ct][r] + bias;
        float g = 0.5f * x * (1.0f + erff(x * 0.70710678118654752f));
        *(u16*)&smem[row * 512 + ((c * 2) ^ ((row & 7) << 4))] = f2bfu(pc * g);
      }
  }
  __syncthreads();

  // ---- GEMM2 prologue: stage tiles 0,1 into bufs 0,1 (2 items each)
  const size_t eB2 = (size_t)((wv < 4) ? e0 : e1) * 524288;
  const char* tsrc = (const char*)w2p + eB2 + (size_t)(wv & 3) * 2048 + (size_t)lane * 16;
  auto STAGE2 = [&](int bb, int n) {
    const char* s = tsrc + (size_t)n * 8192;
    char* d = &smem[32768 + bb * 16384 + (wv >> 2) * 8192 + (wv & 3) * 2048 + lane * 16];
    glds16(s, d);
    glds16(s + 1024, d + 1024);
  };
  STAGE2(0, 0);
  STAGE2(1, 1);

  // preload A frags from sG (8 x bf16x8 = 32 VGPR)
  const int wr2 = wv & 3, wc2 = wv >> 2;
  bf16x8 pa[8];
  {
    int row = wr2 * 16 + l15;
    unsigned sw = (row & 7) << 4;
#pragma unroll
    for (int ks = 0; ks < 8; ++ks)
      pa[ks] = *(const bf16x8*)&smem[row * 512 + ((ks * 64 + lk * 16) ^ sw)];
  }

  float* obase = out + ((size_t)b * SS + st * 64) * HH;
  const int hin = wc2 * 16 + l15;

  // ---- GEMM2: 64 iters, triple-buffered, 1 barrier/iter, counted vmcnt
#pragma unroll 1
  for (int n0 = 0; n0 < 64; ++n0) {
    if (n0 == 0) { WAITV(2); }
    else if (n0 == 63) { WAITV(4); }
    else { WAITV(6); }
    BARRIER();
    const int cb = n0 % 3;
    f32x4 acc2 = zero;
    const char* tb = &smem[32768 + cb * 16384];
#pragma unroll
    for (int ks = 0; ks < 8; ++ks) {
      bf16x8 bv = *(const bf16x8*)(tb + (ks >> 2) * 8192 + hin * 256 +
                                   (((ks & 3) * 64 + lk * 16) ^ ((hin & 7) << 4)));
      acc2 = __builtin_amdgcn_mfma_f32_16x16x32_bf16(pa[ks], bv, acc2, 0, 0, 0);
    }
    const int h = n0 * 32 + hin;
    float bias = p0 * bs2[(size_t)e0 * HH + h] + p1 * bs2[(size_t)e1 * HH + h];
#pragma unroll
    for (int r = 0; r < 4; ++r) {
      int row = wr2 * 16 + lk * 4 + r;
      obase[(size_t)row * HH + h] = acc2[r] + bias;
    }
    if (n0 < 62) STAGE2((n0 + 2) % 3, n0 + 2);
  }
}

// ================= fallback (round-5 proven, needs no packed ws) =================
__global__ void k_pool_logits(const float* __restrict__ hidden,
                              const float* __restrict__ rw,
                              float* __restrict__ logits) {
  const int b  = blockIdx.x >> 6;
  const int hc = (blockIdx.x >> 3) & 7;
  const int sq = blockIdx.x & 7;
  const int t  = threadIdx.x;
  const int tx = t & 63;
  const int qq = t >> 6;
  const int h0 = hc * 256;

  const float* p = hidden + ((size_t)b * SS + sq * 512 + qq * 128) * HH + h0 + tx * 4;
  float4 s = make_float4(0.f, 0.f, 0.f, 0.f);
  for (int i = 0; i < 128; ++i) {
    float4 v = *(const float4*)(p + (size_t)i * HH);
    s.x += v.x; s.y += v.y; s.z += v.z; s.w += v.w;
  }
  __shared__ float ps[4][256];
  __shared__ float pl[256];
  *(float4*)&ps[qq][tx * 4] = s;
  __syncthreads();
  pl[t] = ps[0][t] + ps[1][t] + ps[2][t] + ps[3][t];
  __syncthreads();

  const int e = t >> 3, part = t & 7;
  const float* wrp = rw + (size_t)e * HH + h0 + part * 32;
  float v = 0.f;
#pragma unroll
  for (int m = 0; m < 32; ++m) v += pl[part * 32 + m] * wrp[m];
  v += __shfl_xor(v, 1, 8);
  v += __shfl_xor(v, 2, 8);
  v += __shfl_xor(v, 4, 8);
  if (part == 0) atomicAdd(&logits[b * EE + e], v * (1.0f / (float)SS));
}

__global__ __launch_bounds__(512, 2) void k_ffn_fb(
    const float* __restrict__ hidden, const float* __restrict__ w1,
    const float* __restrict__ b1, const float* __restrict__ w2,
    const float* __restrict__ b2, const int* __restrict__ sel,
    const float* __restrict__ pscale, float* __restrict__ out) {
  __shared__ unsigned char sA[2][64 * 128];
  __shared__ unsigned char sG[64 * 512];

  const int t    = threadIdx.x;
  const int lane = t & 63;
  const int wv   = t >> 6;
  const int wr   = wv >> 2;
  const int wc   = wv & 3;
  const int l15  = lane & 15;
  const int lk   = lane >> 4;

  const int bid = blockIdx.x;
  const int b   = bid & 7;
  const int s0  = (bid >> 3) * 64;

  const int e0 = sel[2 * b], e1 = sel[2 * b + 1];
  const float p0 = pscale[2 * b], p1 = pscale[2 * b + 1];

  const float* hbase = hidden + ((size_t)b * SS + s0) * HH;
  const int srow = t >> 4;
  const int skq  = t & 15;

  float4 R[2];
  const float* wp[4];
#pragma unroll
  for (int ct = 0; ct < 4; ++ct) {
    int cbase = wc * 64 + ct * 16;
    int ec = (cbase < 128) ? e0 : e1;
    int f  = (cbase & 127) + l15;
    wp[ct] = w1 + ((size_t)ec * FF + f) * HH + lk * 8;
  }

  f32x4 zero = {0.f, 0.f, 0.f, 0.f};
  f32x4 acc1[2][4];
#pragma unroll
  for (int i = 0; i < 2; ++i)
#pragma unroll
    for (int j = 0; j < 4; ++j) acc1[i][j] = zero;

#pragma unroll
  for (int p = 0; p < 2; ++p)
    R[p] = *(const float4*)(hbase + (size_t)(srow + 32 * p) * HH + skq * 4);
#pragma unroll
  for (int p = 0; p < 2; ++p) {
    int row = srow + 32 * p;
    int addr = row * 128 + ((skq * 8) ^ ((row & 7) << 4));
    *(uint2*)(&sA[0][addr]) = make_uint2(pk2(R[p].x, R[p].y), pk2(R[p].z, R[p].w));
  }
  __syncthreads();

  for (int it = 0; it < 32; ++it) {
    const int buf = it & 1;
    if (it < 31) {
      const int k0 = (it + 1) * 64;
#pragma unroll
      for (int p = 0; p < 2; ++p)
        R[p] = *(const float4*)(hbase + (size_t)(srow + 32 * p) * HH + k0 + skq * 4);
    }
#pragma unroll
    for (int kk = 0; kk < 2; ++kk) {
      bf16x8 a[2];
#pragma unroll
      for (int rt = 0; rt < 2; ++rt) {
        int row = wr * 32 + rt * 16 + l15;
        a[rt] = *(const bf16x8*)(&sA[buf][row * 128 + ((kk * 64 + lk * 16) ^ ((row & 7) << 4))]);
      }
#pragma unroll
      for (int ct = 0; ct < 4; ++ct) {
        const float* q = wp[ct] + it * 64 + kk * 32;
        bf16x8 bfr = pack8(*(const float4*)q, *(const float4*)(q + 4));
#pragma unroll
        for (int rt = 0; rt < 2; ++rt)
          acc1[rt][ct] = __builtin_amdgcn_mfma_f32_16x16x32_bf16(a[rt], bfr, acc1[rt][ct], 0, 0, 0);
      }
    }
    if (it < 31) {
#pragma unroll
      for (int p = 0; p < 2; ++p) {
        int row = srow + 32 * p;
        int addr = row * 128 + ((skq * 8) ^ ((row & 7) << 4));
        *(uint2*)(&sA[buf ^ 1][addr]) = make_uint2(pk2(R[p].x, R[p].y), pk2(R[p].z, R[p].w));
      }
    }
    __syncthreads();
  }

#pragma unroll
  for (int ct = 0; ct < 4; ++ct) {
    int c = wc * 64 + ct * 16 + l15;
    int ec = (c < 128) ? e0 : e1;
    float pc = (c < 128) ? p0 : p1;
    float bias = b1[ec * FF + (c & 127)];
#pragma unroll
    for (int rt = 0; rt < 2; ++rt)
#pragma unroll
      for (int r = 0; r < 4; ++r) {
        int row = wr * 32 + rt * 16 + lk * 4 + r;
        float x = acc1[rt][ct][r] + bias;
        float g = 0.5f * x * (1.0f + erff(x * 0.70710678118654752f));
        int addr = row * 512 + ((c * 2) ^ ((row & 7) << 4));
        *(u16*)(&sG[addr]) = f2bfu(pc * g);
      }
  }
  __syncthreads();

  bf16x8 pa[2][8];
#pragma unroll
  for (int rt = 0; rt < 2; ++rt) {
    int row = wr * 32 + rt * 16 + l15;
#pragma unroll
    for (int ks = 0; ks < 8; ++ks)
      pa[rt][ks] = *(const bf16x8*)(&sG[row * 512 + ((ks * 64 + lk * 16) ^ ((row & 7) << 4))]);
  }

  float* obase = out + ((size_t)b * SS + s0) * HH;
  for (int ct = 0; ct < 32; ++ct) {
    const int h = wc * 512 + ct * 16 + l15;
    f32x4 acc[2];
    acc[0] = zero; acc[1] = zero;
    const float* q0 = w2 + ((size_t)e0 * HH + h) * FF + lk * 8;
    const float* q1 = w2 + ((size_t)e1 * HH + h) * FF + lk * 8;
#pragma unroll
    for (int ks = 0; ks < 8; ++ks) {
      const float* q = (ks < 4 ? q0 : q1) + (ks & 3) * 32;
      bf16x8 bfr = pack8(*(const float4*)q, *(const float4*)(q + 4));
#pragma unroll
      for (int rt = 0; rt < 2; ++rt)
        acc[rt] = __builtin_amdgcn_mfma_f32_16x16x32_bf16(pa[rt][ks], bfr, acc[rt], 0, 0, 0);
    }
    float bias = p0 * b2[(size_t)e0 * HH + h] + p1 * b2[(size_t)e1 * HH + h];
#pragma unroll
    for (int rt = 0; rt < 2; ++rt)
#pragma unroll
      for (int r = 0; r < 4; ++r) {
        int row = wr * 32 + rt * 16 + lk * 4 + r;
        obase[(size_t)row * HH + h] = acc[rt][r] + bias;
      }
  }
}

extern "C" void kernel_launch(void* const* d_in, const int* in_sizes, int n_in,
                              void* d_out, int out_size, void* d_ws, size_t ws_size,
                              hipStream_t stream) {
  const float* hidden   = (const float*)d_in[0];
  const float* router_w = (const float*)d_in[1];
  const float* router_b = (const float*)d_in[2];
  const float* w1       = (const float*)d_in[3];
  const float* b1       = (const float*)d_in[4];
  const float* w2       = (const float*)d_in[5];
  const float* b2       = (const float*)d_in[6];
  const float* counts   = (const float*)d_in[7];
  const float* drift    = (const float*)d_in[8];
  float* out            = (float*)d_out;

  float* logits = (float*)d_ws;                     // 256 f @ 0
  int*   sel    = (int*)((char*)d_ws + 1024);       // 16 int
  float* pscale = (float*)((char*)d_ws + 1088);     // 16 f
  float* psum   = (float*)((char*)d_ws + 4096);     // BB*HH f (64KB)

  const size_t need_big = 131072 + 2 * WBYTES + HB16_BYTES;

  if (ws_size >= need_big) {
    u16* w1p  = (u16*)((char*)d_ws + 131072);
    u16* w2p  = (u16*)((char*)d_ws + 131072 + WBYTES);
    u16* hb16 = (u16*)((char*)d_ws + 131072 + 2 * WBYTES);
    k_zero<<<68, 256, 0, stream>>>(logits, 17408);
    k_pack<<<8192, 256, 0, stream>>>(w1, w2, w1p, w2p);
    k_pooltile<<<512, 512, 0, stream>>>(hidden, hb16, psum);
    k_logits<<<256, 256, 0, stream>>>(psum, router_w, logits);
    k_topk<<<1, 256, 0, stream>>>(logits, router_b, counts, drift, sel, pscale, out);
    k_ffn2<<<512, 512, 0, stream>>>(hb16, b1, b2, w1p, w2p, sel, pscale, out);
  } else {
    k_zero<<<2, 256, 0, stream>>>(logits, 288);
    k_pool_logits<<<512, 256, 0, stream>>>(hidden, router_w, logits);
    k_topk<<<1, 256, 0, stream>>>(logits, router_b, counts, drift, sel, pscale, out);
    k_ffn_fb<<<512, 512, 0, stream>>>(hidden, w1, b1, w2, b2, sel, pscale, out);
  }
}